// Round 12
// baseline (27.313 us; speedup 1.0000x reference)
//
#include <hip/hip_runtime.h>
#include <math.h>

#define NB 4
#define FRAMES 400
#define NBINS 129
#define HOP 240
#define T_LEN (FRAMES * HOP)   // 96000
#define KLEN 256               // FIR length = 2*(NBINS-1)

#define REC_C { const float cn_ = fmaf(a2, cm, -cm1); cm1 = cm; cm = cn_; }
#define REC_S { const float sn_ = fmaf(a2, sm, -sm1); sm1 = sm; sm = sn_; }

// ---------------------------------------------------------------------------
// Kernel 1 (R10 verbatim — best measured): per (b,frame) windowed
// minimum-phase FIR (256 taps), 128 threads. Parity split: thread n computes
// ker[n] and ker[n+128]. float4 LDS broadcasts; Chebyshev recurrences;
// HW trig/exp (v_sin/v_cos take REVOLUTIONS; n/256 rev is exact).
// ---------------------------------------------------------------------------
__global__ __launch_bounds__(128) void gen_fir(const float* __restrict__ log_mag,
                                               float* __restrict__ kern) {
    const int bf = blockIdx.x;   // 0..NB*FRAMES-1
    const int n  = threadIdx.x;  // 0..127

    __shared__ __align__(16) float  full[132];   // lm[0..128]
    __shared__ __align__(16) float  g[128];      // Xf[k]/128
    __shared__ __align__(16) float2 crci[128];   // (wC[k], wS[k]); w=1 at k=0 else 2

    const float* lm = log_mag + bf * NBINS;
    full[n] = lm[n];
    if (n == 0) full[128] = lm[128];

    const float rev_n = (float)n * (1.0f / 256.0f);
    const float ca = __builtin_amdgcn_cosf(rev_n);   // cos(2*pi*n/256)
    const float sa = __builtin_amdgcn_sinf(rev_n);
    const float a2  = 2.0f * ca;
    const float sgn = (n & 1) ? -1.0f : 1.0f;        // (-1)^n
    __syncthreads();

    const float full0   = full[0];
    const float full128 = full[128];

    // ---- Xf[n] = 2*sum_{m=0..127} full[m] cos(mna) - full[0] + sgn*full[128]
    {
        const float4* f4p = (const float4*)full;
        float cm1 = ca, cm = 1.0f, acc = 0.0f;       // c_{-1}=cos(-a), c_0=1
#pragma unroll 8
        for (int u = 0; u < 32; ++u) {
            const float4 f4 = f4p[u];
            acc = fmaf(f4.x, cm, acc); REC_C;
            acc = fmaf(f4.y, cm, acc); REC_C;
            acc = fmaf(f4.z, cm, acc); REC_C;
            acc = fmaf(f4.w, cm, acc); REC_C;
        }
        const float Xf = 2.0f * acc - full0 + sgn * full128;
        g[n] = Xf * (1.0f / 128.0f);
    }
    __syncthreads();

    // ---- mp[n] = -sum_{k=0..127} g[k] sin(kna)   (k=0 term is 0)
    {
        const float4* g4p = (const float4*)g;
        float sm1 = -sa, sm = 0.0f, acc = 0.0f;      // s_{-1}=sin(-a), s_0=0
#pragma unroll 8
        for (int u = 0; u < 32; ++u) {
            const float4 gv = g4p[u];
            acc = fmaf(gv.x, sm, acc); REC_S;
            acc = fmaf(gv.y, sm, acc); REC_S;
            acc = fmaf(gv.z, sm, acc); REC_S;
            acc = fmaf(gv.w, sm, acc); REC_S;
        }
        const float mp = -acc;
        const float e  = __builtin_amdgcn_exp2f(full[n] * 1.4426950408889634f);
        float rev = mp * 0.15915494309189535f;       // mp / (2*pi)
        rev = rev - floorf(rev);                     // v_fract reduction
        const float smp  = __builtin_amdgcn_sinf(rev);
        const float cmp_ = __builtin_amdgcn_cosf(rev);
        const float sc = (n == 0) ? 1.0f : 2.0f;
        crci[n] = make_float2(sc * e * cmp_, sc * e * smp);
    }
    __syncthreads();

    // ---- ker[n]     = (accE + accO + sgn*e128)/256          (hann = 1)
    //      ker[n+128] = (accE - accO + sgn*e128)/256*(0.5+0.5ca)
    {
        const float e128 = __builtin_amdgcn_exp2f(full128 * 1.4426950408889634f);
        const float4* cc4 = (const float4*)crci;
        float cm1 = ca, cm = 1.0f;     // k=0
        float sm1 = -sa, sm = 0.0f;
        float accE = 0.0f, accO = 0.0f;
#pragma unroll 8
        for (int u = 0; u < 64; ++u) {
            const float4 q = cc4[u];   // C'[2u], S'[2u], C'[2u+1], S'[2u+1]
            accE = fmaf(q.x, cm, accE); accE = fmaf(-q.y, sm, accE);
            REC_C; REC_S;
            accO = fmaf(q.z, cm, accO); accO = fmaf(-q.w, sm, accO);
            REC_C; REC_S;
        }
        const float base = sgn * e128;
        const float s = 1.0f / 256.0f;
        kern[bf * KLEN + n]       = (accE + accO + base) * s;
        kern[bf * KLEN + n + 128] = (accE - accO + base) * s * (0.5f + 0.5f * ca);
    }
}

// ---------------------------------------------------------------------------
// Kernel 2: K-SPLIT time-varying FIR. Lane pair (2i, 2i+1) shares an aligned
// 4-output group te0..te0+3 (groups never straddle a frame boundary:
// boundaries at te=120 mod 240 are multiples of 4). Lane h accumulates taps
// [128h, 128h+128) only -> per thread 33 b128 x-reads + 64 b128 kp-reads =
// 97 LDS instrs for 4 outputs (vs 256 for 2 in R10). Halves combine via
// 8 x __shfl_xor(.,1) (VALU, no LDS); lane h=0 writes a float4.
// Grid (188,4) x 256 thr = 3008 waves = 11.75/CU (occupancy preserved).
// ---------------------------------------------------------------------------
__global__ __launch_bounds__(256) void fir_apply(const float* __restrict__ ex,
                                                 const float* __restrict__ kern,
                                                 float* __restrict__ out) {
    const int b   = blockIdx.y;
    const int t0  = blockIdx.x * 512;
    const int tid = threadIdx.x;
    const int g   = tid >> 1;          // output group 0..127 -> te0 = t0 + 4g
    const int h   = tid & 1;           // tap half: j in [128h, 128h+128)

    __shared__ __align__(16) float  xs[768];        // x[t0-256 .. t0+511]
    __shared__ __align__(16) float2 kp[4][258];     // (kerLo[j], kerHi[j]) per q; +2 pad

    for (int i = tid; i < 768; i += 256) {
        const int t = t0 - 256 + i;
        xs[i] = (t >= 0 && t < T_LEN) ? ex[b * T_LEN + t] : 0.0f;
    }

    // frames needed by this block: f0 .. f0+3 (clamped)
    float src0 = ((float)t0 + 0.5f) * (1.0f / HOP) - 0.5f;
    src0 = fminf(fmaxf(src0, 0.0f), (float)(FRAMES - 1));
    const int f0 = (int)src0;
    const float* kb = kern + b * FRAMES * KLEN;
    for (int i = tid; i < 4 * KLEN; i += 256) {
        const int q = i >> 8;
        const int j = i & 255;
        const int fl = min(f0 + q,     FRAMES - 1);
        const int fh = min(f0 + q + 1, FRAMES - 1);
        kp[q][j] = make_float2(kb[fl * KLEN + j], kb[fh * KLEN + j]);
    }
    __syncthreads();

    const int te0 = t0 + 4 * g;
    if (te0 >= T_LEN) return;          // whole pair exits together

    // interpolation weights (lo shared by te0..te0+3)
    float s0 = ((float)te0 + 0.5f) * (1.0f / HOP) - 0.5f;
    s0 = fminf(fmaxf(s0, 0.0f), (float)(FRAMES - 1));
    const int lo = (int)s0;
    float w[4];
#pragma unroll
    for (int r = 0; r < 4; ++r) {
        float sr = ((float)(te0 + r) + 0.5f) * (1.0f / HOP) - 0.5f;
        sr = fminf(fmaxf(sr, 0.0f), (float)(FRAMES - 1));
        w[r] = sr - (float)lo;
    }

    const float4* kq4 = (const float4*)&kp[lo - f0][0];  // row stride 258*8B = 16B-aligned
    const float4* xs4 = (const float4*)xs;

    float aL0 = 0, aL1 = 0, aL2 = 0, aL3 = 0;
    float aH0 = 0, aH1 = 0, aH2 = 0, aH3 = 0;

    // x[t] lives at xs[t - t0 + 256]; initial window covers x[te0-128h .. +3]
    float4 Rp = xs4[g + 64 - 32 * h];
    const int kbase = 64 * h;          // kq4 index of tap 128h
#pragma unroll 4
    for (int u = 0; u < 32; ++u) {
        const float4 Rc = xs4[g + 63 - 32 * h - u];      // x[te0-128h-4u-4 .. -4u-1]
        const float4 ka = kq4[kbase + 2 * u];            // taps j0, j0+1 (L,H pairs)
        const float4 kb4 = kq4[kbase + 2 * u + 1];       // taps j0+2, j0+3
        // tap j0   : x = (Rp.x, Rp.y, Rp.z, Rp.w) for r=0..3
        aL0 = fmaf(Rp.x, ka.x, aL0); aH0 = fmaf(Rp.x, ka.y, aH0);
        aL1 = fmaf(Rp.y, ka.x, aL1); aH1 = fmaf(Rp.y, ka.y, aH1);
        aL2 = fmaf(Rp.z, ka.x, aL2); aH2 = fmaf(Rp.z, ka.y, aH2);
        aL3 = fmaf(Rp.w, ka.x, aL3); aH3 = fmaf(Rp.w, ka.y, aH3);
        // tap j0+1 : x = (Rc.w, Rp.x, Rp.y, Rp.z)
        aL0 = fmaf(Rc.w, ka.z, aL0); aH0 = fmaf(Rc.w, ka.w, aH0);
        aL1 = fmaf(Rp.x, ka.z, aL1); aH1 = fmaf(Rp.x, ka.w, aH1);
        aL2 = fmaf(Rp.y, ka.z, aL2); aH2 = fmaf(Rp.y, ka.w, aH2);
        aL3 = fmaf(Rp.z, ka.z, aL3); aH3 = fmaf(Rp.z, ka.w, aH3);
        // tap j0+2 : x = (Rc.z, Rc.w, Rp.x, Rp.y)
        aL0 = fmaf(Rc.z, kb4.x, aL0); aH0 = fmaf(Rc.z, kb4.y, aH0);
        aL1 = fmaf(Rc.w, kb4.x, aL1); aH1 = fmaf(Rc.w, kb4.y, aH1);
        aL2 = fmaf(Rp.x, kb4.x, aL2); aH2 = fmaf(Rp.x, kb4.y, aH2);
        aL3 = fmaf(Rp.y, kb4.x, aL3); aH3 = fmaf(Rp.y, kb4.y, aH3);
        // tap j0+3 : x = (Rc.y, Rc.z, Rc.w, Rp.x)
        aL0 = fmaf(Rc.y, kb4.z, aL0); aH0 = fmaf(Rc.y, kb4.w, aH0);
        aL1 = fmaf(Rc.z, kb4.z, aL1); aH1 = fmaf(Rc.z, kb4.w, aH1);
        aL2 = fmaf(Rc.w, kb4.z, aL2); aH2 = fmaf(Rc.w, kb4.w, aH2);
        aL3 = fmaf(Rp.x, kb4.z, aL3); aH3 = fmaf(Rp.x, kb4.w, aH3);
        Rp = Rc;
    }

    // combine tap halves across the lane pair (VALU only)
    aL0 += __shfl_xor(aL0, 1); aH0 += __shfl_xor(aH0, 1);
    aL1 += __shfl_xor(aL1, 1); aH1 += __shfl_xor(aH1, 1);
    aL2 += __shfl_xor(aL2, 1); aH2 += __shfl_xor(aH2, 1);
    aL3 += __shfl_xor(aL3, 1); aH3 += __shfl_xor(aH3, 1);

    if (h == 0) {
        float4 y;
        y.x = aL0 + w[0] * (aH0 - aL0);
        y.y = aL1 + w[1] * (aH1 - aL1);
        y.z = aL2 + w[2] * (aH2 - aL2);
        y.w = aL3 + w[3] * (aH3 - aL3);
        *(float4*)(out + b * T_LEN + te0) = y;   // te0 multiple of 4 -> aligned
    }
}

// ---------------------------------------------------------------------------
extern "C" void kernel_launch(void* const* d_in, const int* in_sizes, int n_in,
                              void* d_out, int out_size, void* d_ws, size_t ws_size,
                              hipStream_t stream) {
    const float* ex      = (const float*)d_in[0];
    const float* log_mag = (const float*)d_in[1];
    float* kern = (float*)d_ws;          // NB*FRAMES*KLEN floats = 1.6 MB
    float* out  = (float*)d_out;

    gen_fir<<<NB * FRAMES, 128, 0, stream>>>(log_mag, kern);

    dim3 grid((T_LEN + 511) / 512, NB);
    fir_apply<<<grid, 256, 0, stream>>>(ex, kern, out);
}

// Round 13
// 24.224 us; speedup vs baseline: 1.1275x; 1.1275x over previous
//
#include <hip/hip_runtime.h>
#include <math.h>

#define NB 4
#define FRAMES 400
#define NBINS 129
#define HOP 240
#define T_LEN (FRAMES * HOP)   // 96000
#define KLEN 256               // FIR length = 2*(NBINS-1)

#define REC_C { const float cn_ = fmaf(a2, cm, -cm1); cm1 = cm; cm = cn_; }
#define REC_S { const float sn_ = fmaf(a2, sm, -sm1); sm1 = sm; sm = sn_; }

// ---------------------------------------------------------------------------
// Kernel 1: K-SPLIT gen. 256 threads: thread (n = tid&127, h = tid>>7)
// accumulates the h-th HALF (64 terms) of each DFT sum for outputs
// (ker[n], ker[n+128]). Chebyshev recurrences seeded mid-stream at
// m0 = 64h via exact integer-argument HW sincos (rev = ((m0*n)&255)/256).
// Halves combine through LDS partials. Serial chain per loop: 64 steps
// (was 128); waves/block: 4 (was 2) -> 25 waves/CU (was 12.5).
// h is wave-uniform -> all coefficient reads stay wave-uniform broadcasts.
// ---------------------------------------------------------------------------
__global__ __launch_bounds__(256) void gen_fir(const float* __restrict__ log_mag,
                                               float* __restrict__ kern) {
    const int bf  = blockIdx.x;    // 0..NB*FRAMES-1
    const int tid = threadIdx.x;   // 0..255
    const int n   = tid & 127;
    const int h   = tid >> 7;      // k/m half: [64h, 64h+64)

    __shared__ __align__(16) float  full[132];     // lm[0..128]
    __shared__ __align__(16) float  pg[2][128];    // loop1 partials (pre-scaled)
    __shared__ __align__(16) float  pm[2][128];    // loop2 partials
    __shared__ __align__(16) float2 crci[128];     // (wC[k], wS[k])
    __shared__ __align__(16) float  pe[2][128];    // loop3 accE partials
    __shared__ __align__(16) float  po[2][128];    // loop3 accO partials

    const float* lm = log_mag + bf * NBINS;
    if (tid < NBINS) full[tid] = lm[tid];

    const float rev_n = (float)n * (1.0f / 256.0f);
    const float ca = __builtin_amdgcn_cosf(rev_n);   // cos(2*pi*n/256)
    const float sa = __builtin_amdgcn_sinf(rev_n);
    const float a2  = 2.0f * ca;
    const float sgn = (n & 1) ? -1.0f : 1.0f;        // (-1)^n

    // recurrence seeds at m0 = 64h: cm=cos(m0 n a), cm1=cos((m0-1) n a), etc.
    float cm0, cm1_0, sm0, sm1_0;
    if (h == 0) {
        cm0 = 1.0f;  cm1_0 = ca;    // cos(0), cos(-na) = ca
        sm0 = 0.0f;  sm1_0 = -sa;   // sin(0), sin(-na) = -sa
    } else {
        const float r64 = (float)((64 * n) & 255) * (1.0f / 256.0f);  // exact
        const float r63 = (float)((63 * n) & 255) * (1.0f / 256.0f);
        cm0   = __builtin_amdgcn_cosf(r64);
        sm0   = __builtin_amdgcn_sinf(r64);
        cm1_0 = __builtin_amdgcn_cosf(r63);
        sm1_0 = __builtin_amdgcn_sinf(r63);
    }
    __syncthreads();

    const float full0   = full[0];
    const float full128 = full[128];

    // ---- loop1 (half): U_h = sum_{m=64h}^{64h+63} full[m] cos(mna)
    //      pg[h][n] = U_h/64 + h-share of (-full0 + sgn*full128)/128
    //      so that g[n] = pg[0][n] + pg[1][n]
    {
        const float4* f4p = (const float4*)full;
        float cm1 = cm1_0, cm = cm0, acc = 0.0f;
#pragma unroll 8
        for (int u = 16 * h; u < 16 * h + 16; ++u) {
            const float4 f4 = f4p[u];
            acc = fmaf(f4.x, cm, acc); REC_C;
            acc = fmaf(f4.y, cm, acc); REC_C;
            acc = fmaf(f4.z, cm, acc); REC_C;
            acc = fmaf(f4.w, cm, acc); REC_C;
        }
        const float share = h ? (sgn * full128) : (-full0);
        pg[h][n] = acc * (1.0f / 64.0f) + share * (1.0f / 128.0f);
    }
    __syncthreads();

    // ---- loop2 (half): V_h = sum_{k=64h}^{64h+63} g[k] sin(kna),
    //      g[k] = pg[0][k] + pg[1][k] folded inline
    {
        const float4* p0 = (const float4*)pg[0];
        const float4* p1 = (const float4*)pg[1];
        float sm1 = sm1_0, sm = sm0, acc = 0.0f;
#pragma unroll 8
        for (int u = 16 * h; u < 16 * h + 16; ++u) {
            const float4 a4 = p0[u];
            const float4 b4 = p1[u];
            acc = fmaf(a4.x + b4.x, sm, acc); REC_S;
            acc = fmaf(a4.y + b4.y, sm, acc); REC_S;
            acc = fmaf(a4.z + b4.z, sm, acc); REC_S;
            acc = fmaf(a4.w + b4.w, sm, acc); REC_S;
        }
        pm[h][n] = acc;
    }
    __syncthreads();

    // ---- crci[n] from mp[n] = -(pm[0][n]+pm[1][n])   (h=0 threads)
    if (h == 0) {
        const float mp = -(pm[0][n] + pm[1][n]);
        const float e  = __builtin_amdgcn_exp2f(full[n] * 1.4426950408889634f);
        float rev = mp * 0.15915494309189535f;       // mp / (2*pi)
        rev = rev - floorf(rev);                     // fract reduction
        const float smp  = __builtin_amdgcn_sinf(rev);
        const float cmp_ = __builtin_amdgcn_cosf(rev);
        const float sc = (n == 0) ? 1.0f : 2.0f;
        crci[n] = make_float2(sc * e * cmp_, sc * e * smp);
    }
    __syncthreads();

    // ---- loop3 (half): accE (even k), accO (odd k) over k in [64h, 64h+64)
    {
        const float4* cc4 = (const float4*)crci;
        float cm1 = cm1_0, cm = cm0;
        float sm1 = sm1_0, sm = sm0;
        float accE = 0.0f, accO = 0.0f;
#pragma unroll 8
        for (int u = 32 * h; u < 32 * h + 32; ++u) {
            const float4 q = cc4[u];   // C'[2u], S'[2u], C'[2u+1], S'[2u+1]
            accE = fmaf(q.x, cm, accE); accE = fmaf(-q.y, sm, accE);
            REC_C; REC_S;
            accO = fmaf(q.z, cm, accO); accO = fmaf(-q.w, sm, accO);
            REC_C; REC_S;
        }
        pe[h][n] = accE;
        po[h][n] = accO;
    }
    __syncthreads();

    // ---- epilogue (h=0 threads): combine halves, window, store
    if (h == 0) {
        const float accE = pe[0][n] + pe[1][n];
        const float accO = po[0][n] + po[1][n];
        const float e128 = __builtin_amdgcn_exp2f(full128 * 1.4426950408889634f);
        const float base = sgn * e128;
        const float s = 1.0f / 256.0f;
        kern[bf * KLEN + n]       = (accE + accO + base) * s;
        kern[bf * KLEN + n + 128] = (accE - accO + base) * s * (0.5f + 0.5f * ca);
    }
}

// ---------------------------------------------------------------------------
// Kernel 2 (R10 verbatim — best measured fir): 256 threads, 2 adjacent
// outputs per thread; kp (kL,kH) interleaved so one ds_read_b128 = 2 taps of
// both kernels; x via b64 + register carry; 8 independent accumulator chains.
// ---------------------------------------------------------------------------
__global__ __launch_bounds__(256) void fir_apply(const float* __restrict__ ex,
                                                 const float* __restrict__ kern,
                                                 float* __restrict__ out) {
    const int b   = blockIdx.y;
    const int t0  = blockIdx.x * 512;
    const int tid = threadIdx.x;

    __shared__ __align__(16) float  xs[768];        // x[t0-255 .. t0+256]
    __shared__ __align__(16) float2 kp[4][258];     // (kerLo[j], kerHi[j]) per q; +2 pad

    for (int i = tid; i < 768; i += 256) {
        const int t = t0 - 255 + i;
        xs[i] = (t >= 0 && t < T_LEN) ? ex[b * T_LEN + t] : 0.0f;
    }

    // frames needed by this block: f0 .. f0+3 (clamped)
    float src0 = ((float)t0 + 0.5f) * (1.0f / HOP) - 0.5f;
    src0 = fminf(fmaxf(src0, 0.0f), (float)(FRAMES - 1));
    const int f0 = (int)src0;
    const float* kb = kern + b * FRAMES * KLEN;
    for (int i = tid; i < 4 * KLEN; i += 256) {
        const int q = i >> 8;
        const int j = i & 255;
        const int fl = min(f0 + q,     FRAMES - 1);
        const int fh = min(f0 + q + 1, FRAMES - 1);
        kp[q][j] = make_float2(kb[fl * KLEN + j], kb[fh * KLEN + j]);
    }
    __syncthreads();

    const int te = t0 + 2 * tid;
    float se = ((float)te + 0.5f) * (1.0f / HOP) - 0.5f;
    se = fminf(fmaxf(se, 0.0f), (float)(FRAMES - 1));
    float so = ((float)te + 1.5f) * (1.0f / HOP) - 0.5f;
    so = fminf(fmaxf(so, 0.0f), (float)(FRAMES - 1));
    const int   lo = (int)se;           // == lo(te+1), boundary-safe by parity
    const float we = se - (float)lo;
    const float wo = so - (float)lo;

    const float4* kq4 = (const float4*)&kp[lo - f0][0];   // (kL[2u],kH[2u],kL[2u+1],kH[2u+1])

    const int base = 2 * tid;           // xs index of x[te] is base+255
    float carry = xs[base + 256];       // x[te+1]
    float aeL = 0.0f, aeH = 0.0f, aoL = 0.0f, aoH = 0.0f;
#pragma unroll 8
    for (int u = 0; u < 128; ++u) {
        const float2 v  = *(const float2*)&xs[base + 254 - 2 * u];  // (x[te-2u-1], x[te-2u])
        const float4 k4 = kq4[u];
        aeL = fmaf(v.y,   k4.x, aeL);  aeH = fmaf(v.y,   k4.y, aeH);   // out e, j=2u
        aoL = fmaf(carry, k4.x, aoL);  aoH = fmaf(carry, k4.y, aoH);   // out o, j=2u
        aeL = fmaf(v.x,   k4.z, aeL);  aeH = fmaf(v.x,   k4.w, aeH);   // out e, j=2u+1
        aoL = fmaf(v.y,   k4.z, aoL);  aoH = fmaf(v.y,   k4.w, aoH);   // out o, j=2u+1
        carry = v.x;
    }

    if (te < T_LEN)     out[b * T_LEN + te]     = (1.0f - we) * aeL + we * aeH;
    if (te + 1 < T_LEN) out[b * T_LEN + te + 1] = (1.0f - wo) * aoL + wo * aoH;
}

// ---------------------------------------------------------------------------
extern "C" void kernel_launch(void* const* d_in, const int* in_sizes, int n_in,
                              void* d_out, int out_size, void* d_ws, size_t ws_size,
                              hipStream_t stream) {
    const float* ex      = (const float*)d_in[0];
    const float* log_mag = (const float*)d_in[1];
    float* kern = (float*)d_ws;          // NB*FRAMES*KLEN floats = 1.6 MB
    float* out  = (float*)d_out;

    gen_fir<<<NB * FRAMES, 256, 0, stream>>>(log_mag, kern);

    dim3 grid((T_LEN + 511) / 512, NB);
    fir_apply<<<grid, 256, 0, stream>>>(ex, kern, out);
}